// Round 12
// baseline (316.233 us; speedup 1.0000x reference)
//
#include <hip/hip_runtime.h>
#include <math.h>

#define NEGV -9000000000000000.0f
#define WPB 16  // waves per block
#define NTHR 1024

__device__ __forceinline__ float wave_sum(float v) {
#pragma unroll
  for (int m = 32; m; m >>= 1) v += __shfl_xor(v, m, 64);
  return v;
}

__device__ __forceinline__ int rl(int v, int l) {
  return __builtin_amdgcn_readlane(v, l);
}

// ---- pack W into global ws: Wp[(r*16+k)*64+e] (float4) = W[r][e][4k..4k+3].
// Lane e then reads Wp + (r<<10)+(k<<6)+e: 64 lanes x 16B contiguous ->
// fully coalesced global_load_dwordx4, L2-resident (128 KB total).
__global__ __launch_bounds__(NTHR) void k_prep(const float* __restrict__ W,
                                               float4* __restrict__ wp) {
  int f = blockIdx.x * NTHR + threadIdx.x;  // 8192 float4s
  float4 v = ((const float4*)W)[f];
  int r = f >> 10, e = (f >> 4) & 63, k = f & 15;
  wp[(((r << 4) + k) << 6) + e] = v;
}

// Wave-uniform loads of x[32..63] (8 float4) -> SGPRs (s_load).
__device__ __forceinline__ void load_xu_hi(const float* __restrict__ emb, int nb,
                                           float4 xu[8]) {
  const float4* xg = (const float4*)(emb + ((size_t)nb << 6) + 32);
#pragma unroll
  for (int j = 0; j < 8; ++j) xu[j] = xg[j];
}

// Wave-uniform loads of the full x row (16 float4).
__device__ __forceinline__ void load_xu_full(const float* __restrict__ emb, int nb,
                                             float4 xu[16]) {
  const float4* xg = (const float4*)(emb + ((size_t)nb << 6));
#pragma unroll
  for (int j = 0; j < 16; ++j) xu[j] = xg[j];
}

// y = tanh(sum_d W[r][lane][d] * xu[d]); W row from packed global (coalesced,
// L2-hit), x preloaded uniform. Same values, same d-ascending fmaf chain as
// all prior rounds -> bit-exact.
__device__ __forceinline__ float transform_pre(const float4 xu[16], int r, int lane,
                                               const float4* __restrict__ wp) {
  const float4* wr = wp + (r << 10) + lane;
  float acc = 0.f;
#pragma unroll
  for (int k = 0; k < 16; ++k) {
    float4 w = wr[k << 6];
    acc = fmaf(w.x, xu[k].x, acc);
    acc = fmaf(w.y, xu[k].y, acc);
    acc = fmaf(w.z, xu[k].z, acc);
    acc = fmaf(w.w, xu[k].w, acc);
  }
  return tanhf(acc);
}

// One scored neighbor (R10 structure, W from packed global). xu_cur holds
// d32..63 for THIS pos; the s_loads for pos were issued right before the
// fence of the previous step, hidden under its DS staging.
__device__ __forceinline__ void score_step(int pos, int lane,
                                           const float4* __restrict__ wp, float* xbuf,
                                           const float* __restrict__ emb, int srt_r,
                                           int srt_nb, int order, float u_e,
                                           float4 wv[16], int& rcur, float& xv,
                                           float& s_mine, float4 xu[8]) {
  int r = rl(srt_r, pos);
  if (r != rcur) {  // wave-uniform; ~7-8 reloads per task (coalesced, L2-hit)
    const float4* wr = wp + (r << 10) + lane;
#pragma unroll
    for (int k = 0; k < 16; ++k) wv[k] = wr[k << 6];
#pragma unroll
    for (int k = 0; k < 16; ++k)
      asm volatile("" : "+v"(wv[k].x), "+v"(wv[k].y), "+v"(wv[k].z), "+v"(wv[k].w));
    rcur = r;
  }
  int nbn = (pos < 63) ? rl(srt_nb, pos + 1) : 0;
  // stage this neighbor's row into per-wave LDS (lower half consumed)
  __builtin_amdgcn_wave_barrier();
  xbuf[lane] = xv;
  __builtin_amdgcn_wave_barrier();
  // prefetch next lane-strided row (vector load, vmcnt domain)
  float xnext = 0.f;
  if (pos < 63) xnext = emb[((size_t)nbn << 6) + lane];
  asm volatile("s_waitcnt lgkmcnt(0)" ::: "memory");  // ds_write + xu s_loads
  __builtin_amdgcn_wave_barrier();
  float acc = 0.f;
#pragma unroll
  for (int k = 0; k < 8; ++k) {  // d 0..31 via LDS broadcast reads
    float4 x = *(const float4*)(xbuf + 4 * k);
    acc = fmaf(wv[k].x, x.x, acc);
    acc = fmaf(wv[k].y, x.y, acc);
    acc = fmaf(wv[k].z, x.z, acc);
    acc = fmaf(wv[k].w, x.w, acc);
  }
#pragma unroll
  for (int k = 8; k < 16; ++k) {  // d 32..63 via SGPR operands
    acc = fmaf(wv[k].x, xu[k - 8].x, acc);
    acc = fmaf(wv[k].y, xu[k - 8].y, acc);
    acc = fmaf(wv[k].z, xu[k - 8].z, acc);
    acc = fmaf(wv[k].w, xu[k - 8].w, acc);
  }
  // issue NEXT xu s_loads; they retire behind the next step's lgkm fence
  if (pos < 63) load_xu_hi(emb, nbn, xu);
  float y = tanhf(acc);
  float totv = wave_sum(u_e * y);
  int n = rl(order, pos);
  if (lane == n) s_mine = totv * (1.0f / 64.0f);
  xv = xnext;
}

// Score 64 neighbors of eid (relation-grouped, W pinned in VGPRs, hybrid
// LDS/SMEM x broadcast, 1-ahead prefetch), masked softmax, top-8
// (value desc, index asc), second masked softmax. Bit-exact.
__device__ __forceinline__ void score_select(int eid, int b, int lane,
                                             const float* __restrict__ emb,
                                             const float4* __restrict__ wp, float* xbuf,
                                             const int* __restrict__ adjE,
                                             const int* __restrict__ adjR,
                                             const float* __restrict__ user_emb,
                                             int& nbr, int& rel, int seli[8],
                                             float wout[8]) {
  nbr = adjE[((size_t)eid << 6) + lane];
  rel = adjR[((size_t)eid << 6) + lane];
  float u_e = user_emb[((size_t)b << 6) + lane];
  // rank of this lane in relation-sorted order (stable within relation)
  int myrank = 0, basec = 0;
  unsigned long long ltmask = (1ull << lane) - 1ull;
#pragma unroll
  for (int rr = 0; rr < 8; ++rr) {
    unsigned long long m = __ballot(rel == rr);
    if (rel == rr) myrank = basec + (int)__popcll(m & ltmask);
    basec += (int)__popcll(m);
  }
  // order[k] = original neighbor index of k-th sorted element (push-permute)
  int order = __builtin_amdgcn_ds_permute(myrank << 2, lane);
  int srt_nb = __shfl(nbr, order, 64);  // neighbor entity of k-th sorted
  int srt_r = __shfl(rel, order, 64);   // relation of k-th sorted

  int nb0 = rl(srt_nb, 0);
  float xv = emb[((size_t)nb0 << 6) + lane];  // prefetch first row
  float4 xu[8];
  load_xu_hi(emb, nb0, xu);  // upper half, uniform s_loads
  float4 wv[16];
  int rcur = -1;
  float s_mine = 0.f;
  for (int pos = 0; pos < 64; ++pos)
    score_step(pos, lane, wp, xbuf, emb, srt_r, srt_nb, order, u_e, wv, rcur, xv,
               s_mine, xu);
  // ---- masked softmax over 64 neighbors (bit-exact) ----
  float sv = (s_mine == 0.0f) ? NEGV : s_mine;
  float mx = sv;
#pragma unroll
  for (int m = 32; m; m >>= 1) mx = fmaxf(mx, __shfl_xor(mx, m, 64));
  float p = expf(sv - mx);
  float Z = wave_sum(p);
  p /= Z;
  // top-8: iterative butterfly argmax with (value desc, index asc)
  float v = p;
  int vi = lane;
  float selv[8];
#pragma unroll
  for (int j = 0; j < 8; ++j) {
    float bv = v;
    int bi = vi;
#pragma unroll
    for (int m = 1; m < 64; m <<= 1) {
      float ov = __shfl_xor(bv, m, 64);
      int oi = __shfl_xor(bi, m, 64);
      if (ov > bv || (ov == bv && oi < bi)) { bv = ov; bi = oi; }
    }
    selv[j] = bv;
    seli[j] = bi;
    if (lane == bi) v = -__builtin_inff();
  }
  // second masked softmax over the 8 selected
  float m8 = -__builtin_inff();
#pragma unroll
  for (int j = 0; j < 8; ++j) {
    float tt = (selv[j] == 0.f) ? NEGV : selv[j];
    selv[j] = tt;
    m8 = fmaxf(m8, tt);
  }
  float Z8 = 0.f;
#pragma unroll
  for (int j = 0; j < 8; ++j) {
    selv[j] = expf(selv[j] - m8);
    Z8 += selv[j];
  }
#pragma unroll
  for (int j = 0; j < 8; ++j) wout[j] = selv[j] / Z8;
}

// ---- user embedding: 4 waves/block, wave = one batch element ----
__global__ __launch_bounds__(256) void k_user(const int* __restrict__ ui,
                                              const float* __restrict__ emb,
                                              const int* __restrict__ clicked,
                                              const float* __restrict__ numc, int hist,
                                              float* __restrict__ user_emb, int ntask) {
  int w = threadIdx.x >> 6, lane = threadIdx.x & 63;
  int b = blockIdx.x * 4 + w;
  if (b >= ntask) return;
  int u = ui[b];
  float acc = 0.f;
  for (int h = 0; h < hist; ++h) {
    int it = clicked[u * hist + h];
    acc += emb[((size_t)it << 6) + lane];
  }
  user_emb[((size_t)b << 6) + lane] = acc * (1.0f / numc[u]);
}

// ---- hop0: score + topsel + transform the 8 selected -> e1, s0w, emb1 ----
// Task map t = blockIdx + gridDim*w spreads small ntask across ALL CUs.
__global__ __launch_bounds__(NTHR, 4) void k_hop0_f(
    const int* __restrict__ ii, const float* __restrict__ emb,
    const float4* __restrict__ wp, const int* __restrict__ adjE,
    const int* __restrict__ adjR, const float* __restrict__ user_emb,
    int* __restrict__ e1, float* __restrict__ s0w, float* __restrict__ emb1,
    int ntask) {
  __shared__ __align__(16) float xb[WPB][64];
  int w = threadIdx.x >> 6, lane = threadIdx.x & 63;
  int tot = gridDim.x * WPB;
  for (int t = blockIdx.x + gridDim.x * w; t < ntask; t += tot) {
    int eid = ii[t];
    int nbr, rel, seli[8];
    float w8[8];
    score_select(eid, t, lane, emb, wp, xb[w], adjE, adjR, user_emb, nbr, rel, seli,
                 w8);
    int nbs[8], rrs[8];
#pragma unroll
    for (int j = 0; j < 8; ++j) {
      int sj = __builtin_amdgcn_readfirstlane(seli[j]);
      nbs[j] = rl(nbr, sj);
      rrs[j] = rl(rel, sj);
    }
    float4 xtA[16], xtB[16];
    load_xu_full(emb, nbs[0], xtA);
#pragma unroll
    for (int j = 0; j < 8; ++j) {  // fully unrolled: xc/xn static per iter
      const float4* xc = (j & 1) ? xtB : xtA;
      float4* xn = (j & 1) ? xtA : xtB;
      if (j < 7) load_xu_full(emb, nbs[j + 1], xn);  // prefetch next selected
      float y = transform_pre(xc, rrs[j], lane, wp);
      emb1[(((size_t)t * 8 + j) << 6) + lane] = y;
      if (lane == 0) {
        e1[t * 8 + j] = nbs[j];
        s0w[t * 8 + j] = w8[j];
      }
    }
  }
}

// ---- hop1: score + topsel + fused aggregation (emb + labels) ----
__global__ __launch_bounds__(NTHR, 4) void k_hop1_f(
    const int* __restrict__ ui, const int* __restrict__ ii, const float* __restrict__ emb,
    const float4* __restrict__ wp, const int* __restrict__ adjE,
    const int* __restrict__ adjR, const float* __restrict__ labels, int np1,
    const float* __restrict__ user_emb, const int* __restrict__ e1,
    const float* __restrict__ emb1, float* __restrict__ emb1p,
    float* __restrict__ lab1p, int ntask) {
  __shared__ __align__(16) float xb[WPB][64];
  int w = threadIdx.x >> 6, lane = threadIdx.x & 63;
  int tot = gridDim.x * WPB;
  for (int bj = blockIdx.x + gridDim.x * w; bj < ntask; bj += tot) {
    int b = bj >> 3;
    int u = ui[b];
    int item = ii[b];
    int eid = e1[bj];
    int nbr, rel, seli[8];
    float w8[8];
    score_select(eid, b, lane, emb, wp, xb[w], adjE, adjR, user_emb, nbr, rel, seli,
                 w8);
    int nbs[8], rrs[8];
#pragma unroll
    for (int k = 0; k < 8; ++k) {
      int sk = __builtin_amdgcn_readfirstlane(seli[k]);
      nbs[k] = rl(nbr, sk);
      rrs[k] = rl(rel, sk);
    }
    float4 xtA[16], xtB[16];
    load_xu_full(emb, nbs[0], xtA);
    float agg = 0.f, labagg = 0.f;
#pragma unroll
    for (int k = 0; k < 8; ++k) {  // fully unrolled: xc/xn static per iter
      const float4* xc = (k & 1) ? xtB : xtA;
      float4* xn = (k & 1) ? xtA : xtB;
      if (k < 7) load_xu_full(emb, nbs[k + 1], xn);  // prefetch next selected
      float y = transform_pre(xc, rrs[k], lane, wp);
      agg = fmaf(w8[k], y, agg);
      float raw2 = labels[(size_t)u * np1 + nbs[k]];  // uniform -> scalar load
      float lab2 = (nbs[k] != item) ? raw2 : 0.5f;
      labagg = fmaf(w8[k], lab2, labagg);
    }
    float base = emb1[((size_t)bj << 6) + lane];
    emb1p[((size_t)bj << 6) + lane] = fmaxf(fmaf(agg, 0.125f, base), 0.f);
    if (lane == 0) {
      float raw1 = labels[(size_t)u * np1 + eid];
      bool hm = (eid != item);
      float l1 = hm ? raw1 : 0.5f;
      bool reset1 = (raw1 != 0.5f) && hm;
      lab1p[bj] = reset1 ? l1 : labagg;
    }
  }
}

__global__ __launch_bounds__(256) void k_final(const int* __restrict__ ii,
                                               const float* __restrict__ emb,
                                               const float* __restrict__ user_emb,
                                               const float* __restrict__ s0,
                                               const float* __restrict__ emb1,
                                               const float* __restrict__ emb1p,
                                               const float* __restrict__ lab1p,
                                               float* __restrict__ out, int bs) {
  int w = threadIdx.x >> 6, lane = threadIdx.x & 63;
  int b = blockIdx.x * 4 + w;
  if (b >= bs) return;
  int item = ii[b];
  float ue = user_emb[((size_t)b << 6) + lane];
  float agg = 0.f, aggp = 0.f, lab = 0.f;
#pragma unroll
  for (int j = 0; j < 8; ++j) {
    float s = s0[b * 8 + j];
    agg = fmaf(s, emb1[(((size_t)b * 8 + j) << 6) + lane], agg);
    aggp = fmaf(s, emb1p[(((size_t)b * 8 + j) << 6) + lane], aggp);
    lab = fmaf(s, lab1p[b * 8 + j], lab);
  }
  float e0 = emb[((size_t)item << 6) + lane];
  float h = fmaxf(fmaf(agg, 0.125f, e0), 0.f);  // relu(agg01 + emb0)
  float h2 = tanhf(fmaf(aggp, 0.125f, h));      // tanh(agg01' + emb0')
  float dot = wave_sum(ue * h2);
  if (lane == 0) {
    out[b] = 1.f / (1.f + expf(-dot));
    out[bs + b] = 1.f / (1.f + expf(-(lab - 0.5f)));
  }
}

extern "C" void kernel_launch(void* const* d_in, const int* in_sizes, int n_in, void* d_out,
                              int out_size, void* d_ws, size_t ws_size, hipStream_t stream) {
  const int* ui = (const int*)d_in[0];
  const int* ii = (const int*)d_in[1];
  const float* emb = (const float*)d_in[2];
  const float* W = (const float*)d_in[3];
  const int* adjE = (const int*)d_in[4];
  const int* adjR = (const int*)d_in[5];
  const int* clicked = (const int*)d_in[6];
  const float* numc = (const float*)d_in[7];
  const float* labels = (const float*)d_in[8];

  int bs = in_sizes[0];
  int np1 = in_sizes[2] / 64;  // n_entity + 1 (= labels row stride = offset)
  int nuser = in_sizes[7];
  int hist = in_sizes[6] / nuser;

  // workspace layout
  float4* wp = (float4*)d_ws;                        // 8192 float4 (128 KB)
  float* user_emb = (float*)(wp + 8192);             // bs*64
  float* s0w = user_emb + (size_t)bs * 64;           // bs*8
  int* e1 = (int*)(s0w + (size_t)bs * 8);            // bs*8
  float* emb1 = (float*)(e1 + (size_t)bs * 8);       // bs*8*64
  float* emb1p = emb1 + (size_t)bs * 8 * 64;         // bs*8*64
  float* lab1p = emb1p + (size_t)bs * 8 * 64;        // bs*8

  int nt0 = bs;      // hop0 tasks
  int nt1 = bs * 8;  // hop1 tasks

  k_prep<<<8, NTHR, 0, stream>>>(W, wp);
  k_user<<<(nt0 + 3) / 4, 256, 0, stream>>>(ui, emb, clicked, numc, hist, user_emb, nt0);
  k_hop0_f<<<512, NTHR, 0, stream>>>(ii, emb, wp, adjE, adjR, user_emb, e1, s0w, emb1,
                                     nt0);
  k_hop1_f<<<512, NTHR, 0, stream>>>(ui, ii, emb, wp, adjE, adjR, labels, np1, user_emb,
                                     e1, emb1, emb1p, lab1p, nt1);
  k_final<<<(nt0 + 3) / 4, 256, 0, stream>>>(ii, emb, user_emb, s0w, emb1, emb1p, lab1p,
                                             (float*)d_out, bs);
}

// Round 13
// 213.747 us; speedup vs baseline: 1.4795x; 1.4795x over previous
//
#include <hip/hip_runtime.h>
#include <math.h>

#define NEGV -9000000000000000.0f
#define WPB 16  // waves per block
#define NTHR 1024

// Packed W in LDS: WL[r][k][e] (float4) = W[r][e][4k..4k+3].
// Lane e reads WL[(r*16+k)*64+e]: 64 lanes stride 16B contiguous ->
// conflict-free ds_read_b128. xb = per-wave x staging.
struct LdsW {
  float4 w[8 * 16 * 64];  // 128 KB
  float xb[WPB][64];      // 4 KB
};

__device__ __forceinline__ float wave_sum(float v) {
#pragma unroll
  for (int m = 32; m; m >>= 1) v += __shfl_xor(v, m, 64);
  return v;
}

__device__ __forceinline__ int rl(int v, int l) {
  return __builtin_amdgcn_readlane(v, l);
}

__device__ __forceinline__ void stage_W(float4* wl, const float* __restrict__ W) {
  const float4* Wg = (const float4*)W;
  for (int f = threadIdx.x; f < 8192; f += NTHR) {
    float4 v = Wg[f];  // coalesced global
    int r = f >> 10, e = (f >> 4) & 63, k = f & 15;
    wl[(((r << 4) + k) << 6) + e] = v;
  }
  __syncthreads();
}

// Wave-uniform loads of x[32..63] (8 float4) -> SGPRs (s_load).
__device__ __forceinline__ void load_xu_hi(const float* __restrict__ emb, int nb,
                                           float4 xu[8]) {
  const float4* xg = (const float4*)(emb + ((size_t)nb << 6) + 32);
#pragma unroll
  for (int j = 0; j < 8; ++j) xu[j] = xg[j];
}

// Wave-uniform loads of the full x row (16 float4).
__device__ __forceinline__ void load_xu_full(const float* __restrict__ emb, int nb,
                                             float4 xu[16]) {
  const float4* xg = (const float4*)(emb + ((size_t)nb << 6));
#pragma unroll
  for (int j = 0; j < 16; ++j) xu[j] = xg[j];
}

// y = tanh(sum_d W[r][lane][d] * xu[d]); W row from LDS, x preloaded uniform.
// Same values, same d-ascending fmaf chain as all prior rounds -> bit-exact.
__device__ __forceinline__ float transform_pre(const float4 xu[16], int r, int lane,
                                               const float4* wl) {
  const float4* wr = wl + (r << 10) + lane;
  float acc = 0.f;
#pragma unroll
  for (int k = 0; k < 16; ++k) {
    float4 w = wr[k << 6];
    acc = fmaf(w.x, xu[k].x, acc);
    acc = fmaf(w.y, xu[k].y, acc);
    acc = fmaf(w.z, xu[k].z, acc);
    acc = fmaf(w.w, xu[k].w, acc);
  }
  return tanhf(acc);
}

// One scored neighbor (R10 structure). xu holds d32..63 for THIS pos (its
// s_loads were issued at the end of the previous step, hidden under it);
// at the end we issue the s_loads for pos+1.
__device__ __forceinline__ void score_step(int pos, int lane, const float4* wl,
                                           float* xbuf, const float* __restrict__ emb,
                                           int srt_r, int srt_nb, int order, float u_e,
                                           float4 wv[16], int& rcur, float& xv,
                                           float& s_mine, float4 xu[8]) {
  int r = rl(srt_r, pos);
  if (r != rcur) {  // wave-uniform; ~7-8 reloads per task
    const float4* wr = wl + (r << 10) + lane;
#pragma unroll
    for (int k = 0; k < 16; ++k) wv[k] = wr[k << 6];
#pragma unroll
    for (int k = 0; k < 16; ++k)
      asm volatile("" : "+v"(wv[k].x), "+v"(wv[k].y), "+v"(wv[k].z), "+v"(wv[k].w));
    rcur = r;
  }
  int nbn = (pos < 63) ? rl(srt_nb, pos + 1) : 0;
  // stage this neighbor's row into per-wave LDS (lower half consumed)
  __builtin_amdgcn_wave_barrier();
  xbuf[lane] = xv;
  __builtin_amdgcn_wave_barrier();
  // prefetch next lane-strided row (vector load, vmcnt domain)
  float xnext = 0.f;
  if (pos < 63) xnext = emb[((size_t)nbn << 6) + lane];
  asm volatile("s_waitcnt lgkmcnt(0)" ::: "memory");  // ds_write + xu s_loads
  __builtin_amdgcn_wave_barrier();
  float acc = 0.f;
#pragma unroll
  for (int k = 0; k < 8; ++k) {  // d 0..31 via LDS broadcast reads
    float4 x = *(const float4*)(xbuf + 4 * k);
    acc = fmaf(wv[k].x, x.x, acc);
    acc = fmaf(wv[k].y, x.y, acc);
    acc = fmaf(wv[k].z, x.z, acc);
    acc = fmaf(wv[k].w, x.w, acc);
  }
#pragma unroll
  for (int k = 8; k < 16; ++k) {  // d 32..63 via SGPR operands
    acc = fmaf(wv[k].x, xu[k - 8].x, acc);
    acc = fmaf(wv[k].y, xu[k - 8].y, acc);
    acc = fmaf(wv[k].z, xu[k - 8].z, acc);
    acc = fmaf(wv[k].w, xu[k - 8].w, acc);
  }
  // issue NEXT xu s_loads; they retire behind the next step's lgkm fence
  if (pos < 63) load_xu_hi(emb, nbn, xu);
  float y = tanhf(acc);
  float totv = wave_sum(u_e * y);
  int n = rl(order, pos);
  if (lane == n) s_mine = totv * (1.0f / 64.0f);
  xv = xnext;
}

// Score 64 neighbors of eid (relation-grouped, W pinned in VGPRs, hybrid
// LDS/SMEM x broadcast, 1-ahead prefetch), masked softmax, top-8
// (value desc, index asc), second masked softmax. Bit-exact.
__device__ __forceinline__ void score_select(int eid, int b, int lane,
                                             const float* __restrict__ emb,
                                             const float4* wl, float* xbuf,
                                             const int* __restrict__ adjE,
                                             const int* __restrict__ adjR,
                                             const float* __restrict__ user_emb,
                                             int& nbr, int& rel, int seli[8],
                                             float wout[8]) {
  nbr = adjE[((size_t)eid << 6) + lane];
  rel = adjR[((size_t)eid << 6) + lane];
  float u_e = user_emb[((size_t)b << 6) + lane];
  // rank of this lane in relation-sorted order (stable within relation)
  int myrank = 0, basec = 0;
  unsigned long long ltmask = (1ull << lane) - 1ull;
#pragma unroll
  for (int rr = 0; rr < 8; ++rr) {
    unsigned long long m = __ballot(rel == rr);
    if (rel == rr) myrank = basec + (int)__popcll(m & ltmask);
    basec += (int)__popcll(m);
  }
  // order[k] = original neighbor index of k-th sorted element (push-permute)
  int order = __builtin_amdgcn_ds_permute(myrank << 2, lane);
  int srt_nb = __shfl(nbr, order, 64);  // neighbor entity of k-th sorted
  int srt_r = __shfl(rel, order, 64);   // relation of k-th sorted

  int nb0 = rl(srt_nb, 0);
  float xv = emb[((size_t)nb0 << 6) + lane];  // prefetch first row
  float4 xu[8];
  load_xu_hi(emb, nb0, xu);  // upper half, uniform s_loads
  float4 wv[16];
  int rcur = -1;
  float s_mine = 0.f;
  for (int pos = 0; pos < 64; ++pos)
    score_step(pos, lane, wl, xbuf, emb, srt_r, srt_nb, order, u_e, wv, rcur, xv,
               s_mine, xu);
  // ---- masked softmax over 64 neighbors (bit-exact) ----
  float sv = (s_mine == 0.0f) ? NEGV : s_mine;
  float mx = sv;
#pragma unroll
  for (int m = 32; m; m >>= 1) mx = fmaxf(mx, __shfl_xor(mx, m, 64));
  float p = expf(sv - mx);
  float Z = wave_sum(p);
  p /= Z;
  // top-8: iterative butterfly argmax with (value desc, index asc)
  float v = p;
  int vi = lane;
  float selv[8];
#pragma unroll
  for (int j = 0; j < 8; ++j) {
    float bv = v;
    int bi = vi;
#pragma unroll
    for (int m = 1; m < 64; m <<= 1) {
      float ov = __shfl_xor(bv, m, 64);
      int oi = __shfl_xor(bi, m, 64);
      if (ov > bv || (ov == bv && oi < bi)) { bv = ov; bi = oi; }
    }
    selv[j] = bv;
    seli[j] = bi;
    if (lane == bi) v = -__builtin_inff();
  }
  // second masked softmax over the 8 selected
  float m8 = -__builtin_inff();
#pragma unroll
  for (int j = 0; j < 8; ++j) {
    float tt = (selv[j] == 0.f) ? NEGV : selv[j];
    selv[j] = tt;
    m8 = fmaxf(m8, tt);
  }
  float Z8 = 0.f;
#pragma unroll
  for (int j = 0; j < 8; ++j) {
    selv[j] = expf(selv[j] - m8);
    Z8 += selv[j];
  }
#pragma unroll
  for (int j = 0; j < 8; ++j) wout[j] = selv[j] / Z8;
}

// ---- user embedding: 4 waves/block, wave = one batch element ----
__global__ __launch_bounds__(256) void k_user(const int* __restrict__ ui,
                                              const float* __restrict__ emb,
                                              const int* __restrict__ clicked,
                                              const float* __restrict__ numc, int hist,
                                              float* __restrict__ user_emb, int ntask) {
  int w = threadIdx.x >> 6, lane = threadIdx.x & 63;
  int b = blockIdx.x * 4 + w;
  if (b >= ntask) return;
  int u = ui[b];
  float acc = 0.f;
  for (int h = 0; h < hist; ++h) {
    int it = clicked[u * hist + h];
    acc += emb[((size_t)it << 6) + lane];
  }
  user_emb[((size_t)b << 6) + lane] = acc * (1.0f / numc[u]);
}

// ---- hop0: score + topsel + transform the 8 selected -> e1, s0w, emb1 ----
// Interleaved task map t = blockIdx + gridDim*w: 1024 tasks -> 4 waves on
// EACH of 256 CUs (R10's wid=blockIdx*WPB+w packed them onto 64 CUs).
__global__ __launch_bounds__(NTHR, 4) void k_hop0_f(
    const int* __restrict__ ii, const float* __restrict__ emb,
    const float* __restrict__ W, const int* __restrict__ adjE,
    const int* __restrict__ adjR, const float* __restrict__ user_emb,
    int* __restrict__ e1, float* __restrict__ s0w, float* __restrict__ emb1,
    int ntask) {
  __shared__ LdsW S;
  stage_W(S.w, W);
  int w = threadIdx.x >> 6, lane = threadIdx.x & 63;
  int tot = gridDim.x * WPB;
  for (int t = blockIdx.x + gridDim.x * w; t < ntask; t += tot) {
    int eid = ii[t];
    int nbr, rel, seli[8];
    float w8[8];
    score_select(eid, t, lane, emb, S.w, S.xb[w], adjE, adjR, user_emb, nbr, rel, seli,
                 w8);
    int nbs[8], rrs[8];
#pragma unroll
    for (int j = 0; j < 8; ++j) {
      int sj = __builtin_amdgcn_readfirstlane(seli[j]);
      nbs[j] = rl(nbr, sj);
      rrs[j] = rl(rel, sj);
    }
    float4 xtA[16], xtB[16];
    load_xu_full(emb, nbs[0], xtA);
#pragma unroll
    for (int j = 0; j < 8; ++j) {  // fully unrolled: xc/xn static per iter
      const float4* xc = (j & 1) ? xtB : xtA;
      float4* xn = (j & 1) ? xtA : xtB;
      if (j < 7) load_xu_full(emb, nbs[j + 1], xn);  // prefetch next selected
      float y = transform_pre(xc, rrs[j], lane, S.w);
      emb1[(((size_t)t * 8 + j) << 6) + lane] = y;
      if (lane == 0) {
        e1[t * 8 + j] = nbs[j];
        s0w[t * 8 + j] = w8[j];
      }
    }
  }
}

// ---- hop1: score + topsel + fused aggregation (emb + labels) ----
__global__ __launch_bounds__(NTHR, 4) void k_hop1_f(
    const int* __restrict__ ui, const int* __restrict__ ii, const float* __restrict__ emb,
    const float* __restrict__ W, const int* __restrict__ adjE,
    const int* __restrict__ adjR, const float* __restrict__ labels, int np1,
    const float* __restrict__ user_emb, const int* __restrict__ e1,
    const float* __restrict__ emb1, float* __restrict__ emb1p,
    float* __restrict__ lab1p, int ntask) {
  __shared__ LdsW S;
  stage_W(S.w, W);
  int w = threadIdx.x >> 6, lane = threadIdx.x & 63;
  int wid = blockIdx.x * WPB + w;
  int tot = gridDim.x * WPB;
  for (int bj = wid; bj < ntask; bj += tot) {
    int b = bj >> 3;
    int u = ui[b];
    int item = ii[b];
    int eid = e1[bj];
    int nbr, rel, seli[8];
    float w8[8];
    score_select(eid, b, lane, emb, S.w, S.xb[w], adjE, adjR, user_emb, nbr, rel, seli,
                 w8);
    int nbs[8], rrs[8];
#pragma unroll
    for (int k = 0; k < 8; ++k) {
      int sk = __builtin_amdgcn_readfirstlane(seli[k]);
      nbs[k] = rl(nbr, sk);
      rrs[k] = rl(rel, sk);
    }
    float4 xtA[16], xtB[16];
    load_xu_full(emb, nbs[0], xtA);
    float agg = 0.f, labagg = 0.f;
#pragma unroll
    for (int k = 0; k < 8; ++k) {  // fully unrolled: xc/xn static per iter
      const float4* xc = (k & 1) ? xtB : xtA;
      float4* xn = (k & 1) ? xtA : xtB;
      if (k < 7) load_xu_full(emb, nbs[k + 1], xn);  // prefetch next selected
      float y = transform_pre(xc, rrs[k], lane, S.w);
      agg = fmaf(w8[k], y, agg);
      float raw2 = labels[(size_t)u * np1 + nbs[k]];  // uniform -> scalar load
      float lab2 = (nbs[k] != item) ? raw2 : 0.5f;
      labagg = fmaf(w8[k], lab2, labagg);
    }
    float base = emb1[((size_t)bj << 6) + lane];
    emb1p[((size_t)bj << 6) + lane] = fmaxf(fmaf(agg, 0.125f, base), 0.f);
    if (lane == 0) {
      float raw1 = labels[(size_t)u * np1 + eid];
      bool hm = (eid != item);
      float l1 = hm ? raw1 : 0.5f;
      bool reset1 = (raw1 != 0.5f) && hm;
      lab1p[bj] = reset1 ? l1 : labagg;
    }
  }
}

__global__ __launch_bounds__(256) void k_final(const int* __restrict__ ii,
                                               const float* __restrict__ emb,
                                               const float* __restrict__ user_emb,
                                               const float* __restrict__ s0,
                                               const float* __restrict__ emb1,
                                               const float* __restrict__ emb1p,
                                               const float* __restrict__ lab1p,
                                               float* __restrict__ out, int bs) {
  int w = threadIdx.x >> 6, lane = threadIdx.x & 63;
  int b = blockIdx.x * 4 + w;
  if (b >= bs) return;
  int item = ii[b];
  float ue = user_emb[((size_t)b << 6) + lane];
  float agg = 0.f, aggp = 0.f, lab = 0.f;
#pragma unroll
  for (int j = 0; j < 8; ++j) {
    float s = s0[b * 8 + j];
    agg = fmaf(s, emb1[(((size_t)b * 8 + j) << 6) + lane], agg);
    aggp = fmaf(s, emb1p[(((size_t)b * 8 + j) << 6) + lane], aggp);
    lab = fmaf(s, lab1p[b * 8 + j], lab);
  }
  float e0 = emb[((size_t)item << 6) + lane];
  float h = fmaxf(fmaf(agg, 0.125f, e0), 0.f);  // relu(agg01 + emb0)
  float h2 = tanhf(fmaf(aggp, 0.125f, h));      // tanh(agg01' + emb0')
  float dot = wave_sum(ue * h2);
  if (lane == 0) {
    out[b] = 1.f / (1.f + expf(-dot));
    out[bs + b] = 1.f / (1.f + expf(-(lab - 0.5f)));
  }
}

extern "C" void kernel_launch(void* const* d_in, const int* in_sizes, int n_in, void* d_out,
                              int out_size, void* d_ws, size_t ws_size, hipStream_t stream) {
  const int* ui = (const int*)d_in[0];
  const int* ii = (const int*)d_in[1];
  const float* emb = (const float*)d_in[2];
  const float* W = (const float*)d_in[3];
  const int* adjE = (const int*)d_in[4];
  const int* adjR = (const int*)d_in[5];
  const int* clicked = (const int*)d_in[6];
  const float* numc = (const float*)d_in[7];
  const float* labels = (const float*)d_in[8];

  int bs = in_sizes[0];
  int np1 = in_sizes[2] / 64;  // n_entity + 1 (= labels row stride = offset)
  int nuser = in_sizes[7];
  int hist = in_sizes[6] / nuser;

  // workspace layout
  float* user_emb = (float*)d_ws;               // bs*64
  float* s0w = user_emb + (size_t)bs * 64;      // bs*8
  int* e1 = (int*)(s0w + (size_t)bs * 8);       // bs*8
  float* emb1 = (float*)(e1 + (size_t)bs * 8);  // bs*8*64
  float* emb1p = emb1 + (size_t)bs * 8 * 64;    // bs*8*64
  float* lab1p = emb1p + (size_t)bs * 8 * 64;   // bs*8

  int nt0 = bs;      // hop0 tasks
  int nt1 = bs * 8;  // hop1 tasks

  k_user<<<(nt0 + 3) / 4, 256, 0, stream>>>(ui, emb, clicked, numc, hist, user_emb, nt0);
  k_hop0_f<<<256, NTHR, 0, stream>>>(ii, emb, W, adjE, adjR, user_emb, e1, s0w, emb1,
                                     nt0);
  k_hop1_f<<<256, NTHR, 0, stream>>>(ui, ii, emb, W, adjE, adjR, labels, np1, user_emb,
                                     e1, emb1, emb1p, lab1p, nt1);
  k_final<<<(nt0 + 3) / 4, 256, 0, stream>>>(ii, emb, user_emb, s0w, emb1, emb1p, lab1p,
                                             (float*)d_out, bs);
}